// Round 1
// baseline (353.571 us; speedup 1.0000x reference)
//
#include <hip/hip_runtime.h>
#include <math.h>

#define NPOS 2048   // n
#define MFFT 4096   // 2n
#define NH 8        // heads
#define PDW 16      // pos_dim
#define NE 64       // E
#define NB 16       // batch

__device__ __forceinline__ float2 cmul(float2 a, float2 b) {
    return make_float2(a.x * b.x - a.y * b.y, a.x * b.y + a.y * b.x);
}

// In-place radix-4 DIF: natural order in -> digit-reversed order out.
__device__ void fft_fwd(float2* sh, int tid) {
    #pragma unroll
    for (int st = 0; st < 6; ++st) {
        const int logL = 12 - 2 * st;
        const int logQ = logL - 2;
        const int Q = 1 << logQ;
        const float cmag = -6.283185307179586f / (float)(1 << logL);
        __syncthreads();
        #pragma unroll
        for (int kk = 0; kk < 4; ++kk) {
            int m = tid + (kk << 8);          // butterfly index 0..1023
            int t = m & (Q - 1);
            int base = ((m >> logQ) << logL) + t;
            float2 x0 = sh[base];
            float2 x1 = sh[base + Q];
            float2 x2 = sh[base + 2 * Q];
            float2 x3 = sh[base + 3 * Q];
            float2 s02 = make_float2(x0.x + x2.x, x0.y + x2.y);
            float2 d02 = make_float2(x0.x - x2.x, x0.y - x2.y);
            float2 s13 = make_float2(x1.x + x3.x, x1.y + x3.y);
            float2 d13 = make_float2(x1.x - x3.x, x1.y - x3.y);
            float2 y0 = make_float2(s02.x + s13.x, s02.y + s13.y);
            float2 y2 = make_float2(s02.x - s13.x, s02.y - s13.y);
            float2 y1 = make_float2(d02.x + d13.y, d02.y - d13.x); // d02 - i*d13
            float2 y3 = make_float2(d02.x - d13.y, d02.y + d13.x); // d02 + i*d13
            float sn, cs;
            float ang = cmag * (float)t;
            sincosf(ang, &sn, &cs);
            float2 w1 = make_float2(cs, sn);
            float2 w2 = cmul(w1, w1);
            float2 w3 = cmul(w2, w1);
            sh[base]         = y0;
            sh[base + Q]     = cmul(y1, w1);
            sh[base + 2 * Q] = cmul(y2, w2);
            sh[base + 3 * Q] = cmul(y3, w3);
        }
    }
}

// In-place radix-4 DIT inverse: exact stage-reverse of fft_fwd.
// Digit-reversed order in -> natural order out. NO 1/M scaling (folded into V).
__device__ void fft_inv(float2* sh, int tid) {
    #pragma unroll
    for (int st = 0; st < 6; ++st) {
        const int logL = 2 + 2 * st;
        const int logQ = logL - 2;
        const int Q = 1 << logQ;
        const float cmag = 6.283185307179586f / (float)(1 << logL);
        __syncthreads();
        #pragma unroll
        for (int kk = 0; kk < 4; ++kk) {
            int m = tid + (kk << 8);
            int t = m & (Q - 1);
            int base = ((m >> logQ) << logL) + t;
            float2 z0 = sh[base];
            float2 z1 = sh[base + Q];
            float2 z2 = sh[base + 2 * Q];
            float2 z3 = sh[base + 3 * Q];
            float sn, cs;
            float ang = cmag * (float)t;
            sincosf(ang, &sn, &cs);
            float2 w1 = make_float2(cs, sn);
            float2 w2 = cmul(w1, w1);
            float2 w3 = cmul(w2, w1);
            float2 u0 = z0;
            float2 u1 = cmul(z1, w1);
            float2 u2 = cmul(z2, w2);
            float2 u3 = cmul(z3, w3);
            float2 s02 = make_float2(u0.x + u2.x, u0.y + u2.y);
            float2 d02 = make_float2(u0.x - u2.x, u0.y - u2.y);
            float2 s13 = make_float2(u1.x + u3.x, u1.y + u3.y);
            float2 d13 = make_float2(u1.x - u3.x, u1.y - u3.y);
            sh[base]         = make_float2(s02.x + s13.x, s02.y + s13.y);
            sh[base + 2 * Q] = make_float2(s02.x - s13.x, s02.y - s13.y);
            sh[base + Q]     = make_float2(d02.x - d13.y, d02.y + d13.x); // d02 + i*d13
            sh[base + 3 * Q] = make_float2(d02.x + d13.y, d02.y - d13.x); // d02 - i*d13
        }
    }
}

#define LN_RELU(G, Bv)                                                        \
    {                                                                         \
        float mu = 0.f;                                                       \
        _Pragma("unroll") for (int i = 0; i < PDW; ++i) mu += h[i];           \
        mu *= (1.0f / PDW);                                                   \
        float var = 0.f;                                                      \
        _Pragma("unroll") for (int i = 0; i < PDW; ++i) {                     \
            float d = h[i] - mu;                                              \
            var += d * d;                                                     \
        }                                                                     \
        var *= (1.0f / PDW);                                                  \
        float inv = 1.0f / sqrtf(var + 1e-5f);                                \
        _Pragma("unroll") for (int i = 0; i < PDW; ++i) {                     \
            float nv = (h[i] - mu) * inv * G[i] + Bv[i];                      \
            r[i] = fmaxf(nv, 0.f);                                            \
        }                                                                     \
    }

// One thread per position p in [0,2048): dpbout[p][h] = dpb(p)
// p=0 gives zero_dpb; p>=1 gives pd[:, p-1].
__global__ __launch_bounds__(256) void dpb_mlp_kernel(
    const float* __restrict__ w0, const float* __restrict__ b0,
    const float* __restrict__ g1, const float* __restrict__ gb1,
    const float* __restrict__ w1, const float* __restrict__ b1,
    const float* __restrict__ g2, const float* __restrict__ gb2,
    const float* __restrict__ w2, const float* __restrict__ b2,
    const float* __restrict__ g3, const float* __restrict__ gb3,
    const float* __restrict__ w3, const float* __restrict__ b3,
    float* __restrict__ dpbout)
{
    int p = blockIdx.x * 256 + threadIdx.x;
    if (p >= NPOS) return;
    float t = (float)p;
    float h[PDW], r[PDW];
    #pragma unroll
    for (int i = 0; i < PDW; ++i) h[i] = t * w0[i] + b0[i];

    LN_RELU(g1, gb1);
    #pragma unroll
    for (int j = 0; j < PDW; ++j) {
        float acc = b1[j];
        #pragma unroll
        for (int i = 0; i < PDW; ++i) acc += r[i] * w1[i * PDW + j];
        h[j] = acc;
    }
    LN_RELU(g2, gb2);
    #pragma unroll
    for (int j = 0; j < PDW; ++j) {
        float acc = b2[j];
        #pragma unroll
        for (int i = 0; i < PDW; ++i) acc += r[i] * w2[i * PDW + j];
        h[j] = acc;
    }
    LN_RELU(g3, gb3);
    #pragma unroll
    for (int hh = 0; hh < NH; ++hh) {
        float acc = b3[hh];
        #pragma unroll
        for (int i = 0; i < PDW; ++i) acc += r[i] * w3[i * NH + hh];
        dpbout[p * NH + hh] = acc;
    }
}

// One block per head: build a[h][4096], forward FFT, store V (digit-reversed, /M folded)
__global__ __launch_bounds__(256) void toeplitz_fft_kernel(
    const float* __restrict__ gamma, const float* __restrict__ dpbout,
    float2* __restrict__ V)
{
    __shared__ float2 sh[MFFT];
    int h = blockIdx.x;
    int tid = threadIdx.x;
    float g = gamma[0];
    float lsg = -log1pf(expf(-g));   // log(sigmoid(g))
    #pragma unroll
    for (int j = 0; j < 16; ++j) {
        int k = tid + (j << 8);
        float val;
        if (k == 0 || k == NPOS) val = dpbout[h];                              // zero_dpb
        else if (k < NPOS)       val = lsg * (float)k + dpbout[k * NH + h];    // pos
        else                     val = lsg * (float)(2 * NPOS - k) + dpbout[(k - NPOS) * NH + h]; // neg
        val = fminf(30.f, fmaxf(-60.f, val));
        sh[k] = make_float2(expf(val) * (1.0f / (float)MFFT), 0.f);
    }
    fft_fwd(sh, tid);
    __syncthreads();
    #pragma unroll
    for (int j = 0; j < 16; ++j) {
        int k = tid + (j << 8);
        V[h * MFFT + k] = sh[k];
    }
}

// One block per (b, h, e-pair): pack 2 real columns into one complex signal,
// FFT(4096) -> multiply by V[h] -> IFFT -> write first 2048 rows.
__global__ __launch_bounds__(256) void conv_kernel(
    const float* __restrict__ x, const float2* __restrict__ V,
    float* __restrict__ out)
{
    __shared__ float2 sh[MFFT];
    int wg = blockIdx.x;
    int pair = wg & 31;
    int bh = wg >> 5;
    int h = bh & (NH - 1);
    int tid = threadIdx.x;

    const float* xp = x + (size_t)bh * NPOS * NE + pair * 2;
    #pragma unroll
    for (int j = 0; j < 8; ++j) {
        int s = tid + (j << 8);
        sh[s] = *reinterpret_cast<const float2*>(xp + (size_t)s * NE);
    }
    #pragma unroll
    for (int j = 8; j < 16; ++j) sh[tid + (j << 8)] = make_float2(0.f, 0.f);

    fft_fwd(sh, tid);
    __syncthreads();

    const float2* Vh = V + h * MFFT;
    #pragma unroll
    for (int j = 0; j < 16; ++j) {
        int k = tid + (j << 8);
        sh[k] = cmul(sh[k], Vh[k]);
    }

    fft_inv(sh, tid);
    __syncthreads();

    float* op = out + (size_t)bh * NPOS * NE + pair * 2;
    #pragma unroll
    for (int j = 0; j < 8; ++j) {
        int s = tid + (j << 8);
        *reinterpret_cast<float2*>(op + (size_t)s * NE) = sh[s];
    }
}

extern "C" void kernel_launch(void* const* d_in, const int* in_sizes, int n_in,
                              void* d_out, int out_size, void* d_ws, size_t ws_size,
                              hipStream_t stream) {
    const float* x     = (const float*)d_in[0];
    const float* gamma = (const float*)d_in[1];
    const float* w0    = (const float*)d_in[2];
    const float* b0    = (const float*)d_in[3];
    const float* g1    = (const float*)d_in[4];
    const float* gb1   = (const float*)d_in[5];
    const float* w1    = (const float*)d_in[6];
    const float* b1    = (const float*)d_in[7];
    const float* g2    = (const float*)d_in[8];
    const float* gb2   = (const float*)d_in[9];
    const float* w2    = (const float*)d_in[10];
    const float* b2    = (const float*)d_in[11];
    const float* g3    = (const float*)d_in[12];
    const float* gb3   = (const float*)d_in[13];
    const float* w3    = (const float*)d_in[14];
    const float* b3    = (const float*)d_in[15];
    float* out = (float*)d_out;

    float*  dpbout = (float*)d_ws;                    // 2048*8 fp32 = 64 KB
    float2* V      = (float2*)((char*)d_ws + 65536);  // 8*4096 float2 = 256 KB

    dpb_mlp_kernel<<<NPOS / 256, 256, 0, stream>>>(w0, b0, g1, gb1, w1, b1,
                                                   g2, gb2, w2, b2, g3, gb3,
                                                   w3, b3, dpbout);
    toeplitz_fft_kernel<<<NH, 256, 0, stream>>>(gamma, dpbout, V);
    conv_kernel<<<NB * NH * 32, 256, 0, stream>>>(x, V, out);
}

// Round 2
// 261.160 us; speedup vs baseline: 1.3539x; 1.3539x over previous
//
#include <hip/hip_runtime.h>
#include <math.h>

#define NPOS 2048   // n
#define MFFT 4096   // 2n
#define NH 8        // heads
#define PDW 16      // pos_dim
#define NE 64       // E
#define NB 16       // batch

// padded LDS index: +1 float2 per 16 float2 (breaks 128B-stride bank aliasing)
#define PP(i) ((i) + ((i) >> 4))
#define SH_SZ (MFFT + MFFT / 16)   // 4352 float2 = 34816 B

__device__ __forceinline__ float2 cmul(float2 a, float2 b) {
    return make_float2(a.x * b.x - a.y * b.y, a.x * b.y + a.y * b.x);
}

// In-place radix-4 DIF: natural order in -> digit-reversed order out.
template <int NT>
__device__ void fft_fwd(float2* sh, int tid) {
    #pragma unroll
    for (int st = 0; st < 6; ++st) {
        const int logL = 12 - 2 * st;
        const int logQ = logL - 2;
        const int Q = 1 << logQ;
        const float cmag = -6.283185307179586f / (float)(1 << logL);
        __syncthreads();
        #pragma unroll
        for (int kk = 0; kk < 1024 / NT; ++kk) {
            int m = tid + kk * NT;            // butterfly index 0..1023
            int t = m & (Q - 1);
            int base = ((m >> logQ) << logL) + t;
            float2 x0 = sh[PP(base)];
            float2 x1 = sh[PP(base + Q)];
            float2 x2 = sh[PP(base + 2 * Q)];
            float2 x3 = sh[PP(base + 3 * Q)];
            float2 s02 = make_float2(x0.x + x2.x, x0.y + x2.y);
            float2 d02 = make_float2(x0.x - x2.x, x0.y - x2.y);
            float2 s13 = make_float2(x1.x + x3.x, x1.y + x3.y);
            float2 d13 = make_float2(x1.x - x3.x, x1.y - x3.y);
            float2 y0 = make_float2(s02.x + s13.x, s02.y + s13.y);
            float2 y2 = make_float2(s02.x - s13.x, s02.y - s13.y);
            float2 y1 = make_float2(d02.x + d13.y, d02.y - d13.x); // d02 - i*d13
            float2 y3 = make_float2(d02.x - d13.y, d02.y + d13.x); // d02 + i*d13
            float sn, cs;
            __sincosf(cmag * (float)t, &sn, &cs);
            float2 w1 = make_float2(cs, sn);
            float2 w2 = cmul(w1, w1);
            float2 w3 = cmul(w2, w1);
            sh[PP(base)]         = y0;
            sh[PP(base + Q)]     = cmul(y1, w1);
            sh[PP(base + 2 * Q)] = cmul(y2, w2);
            sh[PP(base + 3 * Q)] = cmul(y3, w3);
        }
    }
}

// In-place radix-4 DIT inverse: exact stage-reverse of fft_fwd.
// Digit-reversed order in -> natural order out. NO 1/M scaling (folded into V).
template <int NT>
__device__ void fft_inv(float2* sh, int tid) {
    #pragma unroll
    for (int st = 0; st < 6; ++st) {
        const int logL = 2 + 2 * st;
        const int logQ = logL - 2;
        const int Q = 1 << logQ;
        const float cmag = 6.283185307179586f / (float)(1 << logL);
        __syncthreads();
        #pragma unroll
        for (int kk = 0; kk < 1024 / NT; ++kk) {
            int m = tid + kk * NT;
            int t = m & (Q - 1);
            int base = ((m >> logQ) << logL) + t;
            float2 z0 = sh[PP(base)];
            float2 z1 = sh[PP(base + Q)];
            float2 z2 = sh[PP(base + 2 * Q)];
            float2 z3 = sh[PP(base + 3 * Q)];
            float sn, cs;
            __sincosf(cmag * (float)t, &sn, &cs);
            float2 w1 = make_float2(cs, sn);
            float2 w2 = cmul(w1, w1);
            float2 w3 = cmul(w2, w1);
            float2 u0 = z0;
            float2 u1 = cmul(z1, w1);
            float2 u2 = cmul(z2, w2);
            float2 u3 = cmul(z3, w3);
            float2 s02 = make_float2(u0.x + u2.x, u0.y + u2.y);
            float2 d02 = make_float2(u0.x - u2.x, u0.y - u2.y);
            float2 s13 = make_float2(u1.x + u3.x, u1.y + u3.y);
            float2 d13 = make_float2(u1.x - u3.x, u1.y - u3.y);
            sh[PP(base)]         = make_float2(s02.x + s13.x, s02.y + s13.y);
            sh[PP(base + 2 * Q)] = make_float2(s02.x - s13.x, s02.y - s13.y);
            sh[PP(base + Q)]     = make_float2(d02.x - d13.y, d02.y + d13.x); // d02 + i*d13
            sh[PP(base + 3 * Q)] = make_float2(d02.x + d13.y, d02.y - d13.x); // d02 - i*d13
        }
    }
}

#define LN_RELU(G, Bv)                                                        \
    {                                                                         \
        float mu = 0.f;                                                       \
        _Pragma("unroll") for (int i = 0; i < PDW; ++i) mu += h[i];           \
        mu *= (1.0f / PDW);                                                   \
        float var = 0.f;                                                      \
        _Pragma("unroll") for (int i = 0; i < PDW; ++i) {                     \
            float d = h[i] - mu;                                              \
            var += d * d;                                                     \
        }                                                                     \
        var *= (1.0f / PDW);                                                  \
        float inv = 1.0f / sqrtf(var + 1e-5f);                                \
        _Pragma("unroll") for (int i = 0; i < PDW; ++i) {                     \
            float nv = (h[i] - mu) * inv * G[i] + Bv[i];                      \
            r[i] = fmaxf(nv, 0.f);                                            \
        }                                                                     \
    }

// One thread per position p in [0,2048): dpbout[p][h] = dpb(p)
__global__ __launch_bounds__(256) void dpb_mlp_kernel(
    const float* __restrict__ w0, const float* __restrict__ b0,
    const float* __restrict__ g1, const float* __restrict__ gb1,
    const float* __restrict__ w1, const float* __restrict__ b1,
    const float* __restrict__ g2, const float* __restrict__ gb2,
    const float* __restrict__ w2, const float* __restrict__ b2,
    const float* __restrict__ g3, const float* __restrict__ gb3,
    const float* __restrict__ w3, const float* __restrict__ b3,
    float* __restrict__ dpbout)
{
    int p = blockIdx.x * 256 + threadIdx.x;
    if (p >= NPOS) return;
    float t = (float)p;
    float h[PDW], r[PDW];
    #pragma unroll
    for (int i = 0; i < PDW; ++i) h[i] = t * w0[i] + b0[i];

    LN_RELU(g1, gb1);
    #pragma unroll
    for (int j = 0; j < PDW; ++j) {
        float acc = b1[j];
        #pragma unroll
        for (int i = 0; i < PDW; ++i) acc += r[i] * w1[i * PDW + j];
        h[j] = acc;
    }
    LN_RELU(g2, gb2);
    #pragma unroll
    for (int j = 0; j < PDW; ++j) {
        float acc = b2[j];
        #pragma unroll
        for (int i = 0; i < PDW; ++i) acc += r[i] * w2[i * PDW + j];
        h[j] = acc;
    }
    LN_RELU(g3, gb3);
    #pragma unroll
    for (int hh = 0; hh < NH; ++hh) {
        float acc = b3[hh];
        #pragma unroll
        for (int i = 0; i < PDW; ++i) acc += r[i] * w3[i * NH + hh];
        dpbout[p * NH + hh] = acc;
    }
}

// One block per head (1024 threads): build a[h][4096], fwd FFT, store V
// (digit-reversed order, 1/M folded in).
__global__ __launch_bounds__(1024) void toeplitz_fft_kernel(
    const float* __restrict__ gamma, const float* __restrict__ dpbout,
    float2* __restrict__ V)
{
    __shared__ float2 sh[SH_SZ];
    int h = blockIdx.x;
    int tid = threadIdx.x;
    float g = gamma[0];
    float lsg = -log1pf(expf(-g));   // log(sigmoid(g))
    #pragma unroll
    for (int j = 0; j < 4; ++j) {
        int k = tid + (j << 10);
        float val;
        if (k == 0 || k == NPOS) val = dpbout[h];                              // zero_dpb
        else if (k < NPOS)       val = lsg * (float)k + dpbout[k * NH + h];    // pos
        else                     val = lsg * (float)(2 * NPOS - k) + dpbout[(k - NPOS) * NH + h]; // neg
        val = fminf(30.f, fmaxf(-60.f, val));
        sh[PP(k)] = make_float2(expf(val) * (1.0f / (float)MFFT), 0.f);
    }
    fft_fwd<1024>(sh, tid);
    __syncthreads();
    #pragma unroll
    for (int j = 0; j < 4; ++j) {
        int k = tid + (j << 10);
        V[h * MFFT + k] = sh[PP(k)];
    }
}

// One block per (b, h, e-pair), 512 threads. Block index remapped so all 32
// pair-blocks of one (b,h) land on the SAME XCD (wg%8 round-robin): the 8
// blocks sharing each 64B line of x/out then share one L2 -> reads fetched
// once, partial writes merge to full lines.
__global__ __launch_bounds__(512) void conv_kernel(
    const float* __restrict__ x, const float2* __restrict__ V,
    float* __restrict__ out)
{
    __shared__ float2 sh[SH_SZ];
    int wg = blockIdx.x;
    int xcd = wg & 7;
    int slot = wg >> 3;            // 0..511
    int pair = slot & 31;
    int bh = ((slot >> 5) << 3) | xcd;   // 0..127, 16 bh per XCD
    int h = bh & (NH - 1);
    int tid = threadIdx.x;

    const float* xp = x + (size_t)bh * NPOS * NE + pair * 2;
    #pragma unroll
    for (int j = 0; j < 4; ++j) {
        int s = tid + (j << 9);
        sh[PP(s)] = *reinterpret_cast<const float2*>(xp + (size_t)s * NE);
    }
    #pragma unroll
    for (int j = 4; j < 8; ++j) sh[PP(tid + (j << 9))] = make_float2(0.f, 0.f);

    fft_fwd<512>(sh, tid);
    __syncthreads();

    const float2* Vh = V + h * MFFT;
    #pragma unroll
    for (int j = 0; j < 8; ++j) {
        int k = tid + (j << 9);
        sh[PP(k)] = cmul(sh[PP(k)], Vh[k]);
    }

    fft_inv<512>(sh, tid);
    __syncthreads();

    float* op = out + (size_t)bh * NPOS * NE + pair * 2;
    #pragma unroll
    for (int j = 0; j < 4; ++j) {
        int s = tid + (j << 9);
        *reinterpret_cast<float2*>(op + (size_t)s * NE) = sh[PP(s)];
    }
}

extern "C" void kernel_launch(void* const* d_in, const int* in_sizes, int n_in,
                              void* d_out, int out_size, void* d_ws, size_t ws_size,
                              hipStream_t stream) {
    const float* x     = (const float*)d_in[0];
    const float* gamma = (const float*)d_in[1];
    const float* w0    = (const float*)d_in[2];
    const float* b0    = (const float*)d_in[3];
    const float* g1    = (const float*)d_in[4];
    const float* gb1   = (const float*)d_in[5];
    const float* w1    = (const float*)d_in[6];
    const float* b1    = (const float*)d_in[7];
    const float* g2    = (const float*)d_in[8];
    const float* gb2   = (const float*)d_in[9];
    const float* w2    = (const float*)d_in[10];
    const float* b2    = (const float*)d_in[11];
    const float* g3    = (const float*)d_in[12];
    const float* gb3   = (const float*)d_in[13];
    const float* w3    = (const float*)d_in[14];
    const float* b3    = (const float*)d_in[15];
    float* out = (float*)d_out;

    float*  dpbout = (float*)d_ws;                    // 2048*8 fp32 = 64 KB
    float2* V      = (float2*)((char*)d_ws + 65536);  // 8*4096 float2 = 256 KB

    dpb_mlp_kernel<<<NPOS / 256, 256, 0, stream>>>(w0, b0, g1, gb1, w1, b1,
                                                   g2, gb2, w2, b2, g3, gb3,
                                                   w3, b3, dpbout);
    toeplitz_fft_kernel<<<NH, 1024, 0, stream>>>(gamma, dpbout, V);
    conv_kernel<<<NB * NH * 32, 512, 0, stream>>>(x, V, out);
}